// Round 10
// baseline (129.809 us; speedup 1.0000x reference)
//
#include <hip/hip_runtime.h>
#include <hip/hip_bf16.h>
#include <hip/hip_fp8.h>

// Problem shape (fixed by setup_inputs)
#define SEQ   16384
#define DIN_  2048
#define DOUT_ 1024
#define NE_   8
#define TPE   (SEQ / NE_)   // 2048 tokens per expert
#define NT    (DIN_ / 64)   // 32 K-tiles of 64

typedef __bf16 bf16x8 __attribute__((ext_vector_type(8)));
typedef __bf16 bf16x4 __attribute__((ext_vector_type(4)));
typedef float  f32x4  __attribute__((ext_vector_type(4)));
typedef float  f32x16 __attribute__((ext_vector_type(16)));

// async global->LDS, 16B per lane. LDS dest must be wave-linear (base + lane*16).
#define GLD(gp, lp) __builtin_amdgcn_global_load_lds( \
    (const __attribute__((address_space(1))) unsigned int*)(gp), \
    (__attribute__((address_space(3))) unsigned int*)(lp), 16, 0, 0)

// Reference fp8_round with the tile-wide divide hoisted: r = v*(1/scale)
__device__ __forceinline__ float fp8_round_dq_m(float v, float sinv, float s) {
    float r = v * sinv;
    r = fminf(fmaxf(r, -448.0f), 448.0f);
    __hip_fp8_e4m3 q(r);   // OCP e4m3fn, RNE, saturated
    return (float)q * s;
}

// ---------------- activation quant-dequant: 1x128 tiles, 4 rows per block ----------------
__global__ __launch_bounds__(256) void quant_x_kernel(const float* __restrict__ X,
                                                      __bf16* __restrict__ Xq) {
    const int t    = threadIdx.x;
    const int lane = t & 63;
    const int wave = t >> 6;
    const int tile = wave * 4 + (lane >> 4);   // 0..15
    const int sub  = lane & 15;
    const size_t off = (size_t)tile * 128 + sub * 8;

    const int row0 = blockIdx.x * 4;
    float4 v0[4], v1[4];
    float mx[4];
    #pragma unroll
    for (int r = 0; r < 4; ++r) {
        const float* p = X + (size_t)(row0 + r) * DIN_ + off;
        v0[r] = *(const float4*)p;
        v1[r] = *(const float4*)(p + 4);
        mx[r] = fmaxf(fmaxf(fmaxf(fabsf(v0[r].x), fabsf(v0[r].y)),
                            fmaxf(fabsf(v0[r].z), fabsf(v0[r].w))),
                      fmaxf(fmaxf(fabsf(v1[r].x), fabsf(v1[r].y)),
                            fmaxf(fabsf(v1[r].z), fabsf(v1[r].w))));
    }
    #pragma unroll
    for (int o = 1; o < 16; o <<= 1) {
        #pragma unroll
        for (int r = 0; r < 4; ++r)
            mx[r] = fmaxf(mx[r], __shfl_xor(mx[r], o, 64));
    }
    #pragma unroll
    for (int r = 0; r < 4; ++r) {
        const float s    = fmaxf(mx[r], 1e-12f) / 448.0f;
        const float sinv = 1.0f / s;
        bf16x8 o;
        o[0] = (__bf16)fp8_round_dq_m(v0[r].x, sinv, s);
        o[1] = (__bf16)fp8_round_dq_m(v0[r].y, sinv, s);
        o[2] = (__bf16)fp8_round_dq_m(v0[r].z, sinv, s);
        o[3] = (__bf16)fp8_round_dq_m(v0[r].w, sinv, s);
        o[4] = (__bf16)fp8_round_dq_m(v1[r].x, sinv, s);
        o[5] = (__bf16)fp8_round_dq_m(v1[r].y, sinv, s);
        o[6] = (__bf16)fp8_round_dq_m(v1[r].z, sinv, s);
        o[7] = (__bf16)fp8_round_dq_m(v1[r].w, sinv, s);
        *(bf16x8*)(Xq + (size_t)(row0 + r) * DIN_ + off) = o;
    }
}

// ---------------- weight quant-dequant: 128x128 blocks ----------------
__global__ __launch_bounds__(256) void quant_w_kernel(const float* __restrict__ W,
                                                      __bf16* __restrict__ Wq) {
    const int rb = blockIdx.x >> 4;
    const int cb = blockIdx.x & 15;
    const int t  = threadIdx.x;

    const float* base = W + (size_t)(rb * 128) * DIN_ + cb * 128;
    const int r0 = t >> 5;
    const int c0 = (t & 31) * 4;

    float4 v[16];
    float m = 0.0f;
    #pragma unroll
    for (int i = 0; i < 16; ++i) {
        v[i] = *(const float4*)(base + (size_t)(i * 8 + r0) * DIN_ + c0);
        m = fmaxf(m, fmaxf(fmaxf(fabsf(v[i].x), fabsf(v[i].y)),
                           fmaxf(fabsf(v[i].z), fabsf(v[i].w))));
    }
    #pragma unroll
    for (int off = 1; off < 64; off <<= 1)
        m = fmaxf(m, __shfl_xor(m, off, 64));
    __shared__ float smx[4];
    if ((t & 63) == 0) smx[t >> 6] = m;
    __syncthreads();
    const float amax = fmaxf(fmaxf(smx[0], smx[1]), fmaxf(smx[2], smx[3]));
    const float s    = fmaxf(amax, 1e-12f) / 448.0f;
    const float sinv = 1.0f / s;

    __bf16* obase = Wq + (size_t)(rb * 128) * DIN_ + cb * 128;
    #pragma unroll
    for (int i = 0; i < 16; ++i) {
        bf16x4 o;
        o[0] = (__bf16)fp8_round_dq_m(v[i].x, sinv, s);
        o[1] = (__bf16)fp8_round_dq_m(v[i].y, sinv, s);
        o[2] = (__bf16)fp8_round_dq_m(v[i].z, sinv, s);
        o[3] = (__bf16)fp8_round_dq_m(v[i].w, sinv, s);
        *(bf16x4*)(obase + (size_t)(i * 8 + r0) * DIN_ + c0) = o;
    }
}

// ---------------- grouped GEMM: 256x256, BK=64, 32x32x16 MFMA ---------------------------
// Layout identical to R8: 4 regions [256 rows][128 B], swizzle slot(3b) ^= row&7,
// lane-linear GLD dest, inverse-swizzled 128B-coalesced source.
// Per-wave: 128x64 out = 4 mf x 2 nf frags of 32x32, acc[4][2] f32x16.
// A/B frag (32x32x16): row = lane&31, k = (lane>>5)*8 + j  -> one b128 per (frag,kstep).
// C/D frag (verified m74/m101): col = lane&31, row = (reg&3) + 8*(reg>>2) + 4*(lane>>5).
// Schedule = R8 counted pre-read (1 phase ahead), 4 phases/K-tile, 8 MFMA each:
//   ph1: MFMA(mf0-1,kh0) | pre aB=A(kh0,mf2-3)[4]  | lgkm(4)
//   ph2: MFMA(mf2-3,kh0) | pre aA=A(kh1,mf0-1)+b1=B(kh1)[8] | lgkm(8)
//   ph3: MFMA(mf0-1,kh1) | pre aB=A(kh1,mf2-3)[4]  | lgkm(4) | stage B(kt+2) | vmcnt(4|0)
//   ph4: MFMA(mf2-3,kh1) | pre next-tile aA,b0[8]  | lgkm(8|0) | stage A(kt+2)
// VM ledger (4 GLD/stage): steady outstanding {B(kt+1),A(kt+1),B(kt+2)} at ph3 gate ->
// vmcnt(4) = tile kt+1 landed for ph4's pre-reads; tails kt>=NT-2 -> vmcnt(0).
__global__ __launch_bounds__(512, 2) void gemm_kernel(const __bf16* __restrict__ X,
                                                      const __bf16* __restrict__ W,
                                                      float* __restrict__ out) {
    __shared__ __align__(16) unsigned char lds[131072];

    // T1: bijective XCD swizzle; 256 blocks = 8 XCDs x 32 (one expert per XCD)
    const int bid  = blockIdx.x;
    const int wgid = (bid & 7) * 32 + (bid >> 3);
    const int e    = wgid >> 5;
    const int tile = wgid & 31;
    const int brow = tile >> 2;   // 0..7
    const int bcol = tile & 3;    // 0..3

    const int t    = threadIdx.x;
    const int lane = t & 63;
    const int wave = t >> 6;
    const int wm   = wave >> 2;   // 0..1
    const int wn   = wave & 3;    // 0..3
    const int l31  = lane & 31;
    const int l5   = lane >> 5;

    const __bf16* Xt = X + (size_t)(e * TPE + brow * 256) * DIN_;
    const __bf16* Wt = W + (size_t)(e * DOUT_ + bcol * 256) * DIN_;

    // stage one full tile (32 KiB): 4 GLD16/thread, linear dest, inverse-swizzled source
    auto stage = [&](int j, bool isA) {
        if (j >= NT) return;
        const unsigned base = (isA ? 0u : 65536u) + (unsigned)(j & 1) * 32768u;
        const __bf16* src = isA ? Xt : Wt;
        #pragma unroll
        for (int i = 0; i < 4; ++i) {
            const unsigned p = (unsigned)i * 8192u + (unsigned)t * 16u;
            const unsigned q = p ^ (((p >> 7) & 7u) << 4);   // involution
            GLD(src + (size_t)(q >> 7) * DIN_ + j * 64 + ((q & 127u) >> 1),
                &lds[base + p]);
        }
    };

    // fragment read: logical (row, 16B-slot) with swizzle
    auto ldf = [&](unsigned base, int row, int slot) -> bf16x8 {
        unsigned p = (unsigned)row * 128u + (unsigned)slot * 16u;
        p ^= ((p >> 7) & 7u) << 4;
        return *(const bf16x8*)&lds[base + p];
    };

    bf16x8 aA[2][2], aB[2][2], b0[2][2], b1[2][2];
    f32x16 acc[4][2] = {};

    #define ABASE(buf) ((unsigned)(buf) * 32768u)
    #define BBASE(buf) (65536u + (unsigned)(buf) * 32768u)
    // dst[m][k] = A frag rows (mfb+m)*32, kstep kh*2+k
    #define PRE_A2(dst, buf, kh, mfb) \
        { _Pragma("unroll") for (int m_ = 0; m_ < 2; ++m_) \
            _Pragma("unroll") for (int k_ = 0; k_ < 2; ++k_) \
                dst[m_][k_] = ldf(ABASE(buf), wm * 128 + ((mfb) + m_) * 32 + l31, \
                                  ((kh) * 2 + k_) * 2 + l5); }
    #define PRE_B2(dst, buf, kh) \
        { _Pragma("unroll") for (int n_ = 0; n_ < 2; ++n_) \
            _Pragma("unroll") for (int k_ = 0; k_ < 2; ++k_) \
                dst[n_][k_] = ldf(BBASE(buf), wn * 64 + n_ * 32 + l31, \
                                  ((kh) * 2 + k_) * 2 + l5); }
    // 8 MFMA; k outer so the 4 dependent pairs are spaced by 4 independents
    #define MFMA8(mfb, aset, bset) \
        { _Pragma("unroll") for (int k_ = 0; k_ < 2; ++k_) \
            _Pragma("unroll") for (int m_ = 0; m_ < 2; ++m_) \
                _Pragma("unroll") for (int n_ = 0; n_ < 2; ++n_) \
                    acc[(mfb) + m_][n_] = __builtin_amdgcn_mfma_f32_32x32x16_bf16( \
                        aset[m_][k_], bset[n_][k_], acc[(mfb) + m_][n_], 0, 0, 0); }

    // prologue: tiles 0,1 (16 GLD, tile0 oldest); wait tile0 landed
    stage(0, false); stage(0, true); stage(1, false); stage(1, true);
    asm volatile("s_waitcnt vmcnt(8)" ::: "memory");
    __builtin_amdgcn_s_barrier();
    PRE_A2(aA, 0, 0, 0);
    PRE_B2(b0, 0, 0);

    for (int kt = 0; kt < NT; ++kt) {
        const int buf = kt & 1;

        // ---- phase 1: kh0 mf0-1 (aA, b0) ----
        PRE_A2(aB, buf, 0, 2);                // for ph2
        asm volatile("s_waitcnt lgkmcnt(4)" ::: "memory");   // drain aA,b0
        __builtin_amdgcn_sched_barrier(0);
        __builtin_amdgcn_s_setprio(1);
        MFMA8(0, aA, b0);
        __builtin_amdgcn_s_setprio(0);
        __builtin_amdgcn_s_barrier();

        // ---- phase 2: kh0 mf2-3 (aB, b0) ----
        PRE_A2(aA, buf, 1, 0);                // for ph3
        PRE_B2(b1, buf, 1);
        asm volatile("s_waitcnt lgkmcnt(8)" ::: "memory");   // drain aB
        __builtin_amdgcn_sched_barrier(0);
        __builtin_amdgcn_s_setprio(1);
        MFMA8(2, aB, b0);
        __builtin_amdgcn_s_setprio(0);
        __builtin_amdgcn_s_barrier();

        // ---- phase 3: kh1 mf0-1 (aA, b1); B(buf) reads drained -> stage B(kt+2) ----
        PRE_A2(aB, buf, 1, 2);                // for ph4
        asm volatile("s_waitcnt lgkmcnt(4)" ::: "memory");   // drain aA,b1
        __builtin_amdgcn_sched_barrier(0);
        stage(kt + 2, false);
        __builtin_amdgcn_s_setprio(1);
        MFMA8(0, aA, b1);
        __builtin_amdgcn_s_setprio(0);
        if (kt < NT - 2) asm volatile("s_waitcnt vmcnt(4)" ::: "memory");
        else             asm volatile("s_waitcnt vmcnt(0)" ::: "memory");
        __builtin_amdgcn_s_barrier();

        // ---- phase 4: kh1 mf2-3 (aB, b1); A(buf) reads drained -> stage A(kt+2) ----
        if (kt < NT - 1) {
            PRE_A2(aA, buf ^ 1, 0, 0);        // next tile
            PRE_B2(b0, buf ^ 1, 0);
        }
        if (kt < NT - 1) asm volatile("s_waitcnt lgkmcnt(8)" ::: "memory");  // drain aB
        else             asm volatile("s_waitcnt lgkmcnt(0)" ::: "memory");
        __builtin_amdgcn_sched_barrier(0);
        stage(kt + 2, true);
        __builtin_amdgcn_s_setprio(1);
        MFMA8(2, aB, b1);
        __builtin_amdgcn_s_setprio(0);
        __builtin_amdgcn_s_barrier();
    }

    // epilogue: 32x32 C/D mapping col = lane&31, row = (reg&3) + 8*(reg>>2) + 4*(lane>>5)
    // -> each 32-lane group writes 32 consecutive f32 = 128B lines (fully coalesced)
    const int orow0 = e * TPE + brow * 256 + wm * 128;
    const int ocol0 = bcol * 256 + wn * 64;
    #pragma unroll
    for (int mf = 0; mf < 4; ++mf)
        #pragma unroll
        for (int nf = 0; nf < 2; ++nf)
            #pragma unroll
            for (int r = 0; r < 16; ++r) {
                const int row = orow0 + mf * 32 + (r & 3) + 8 * (r >> 2) + 4 * l5;
                const int col = ocol0 + nf * 32 + l31;
                out[(size_t)row * DOUT_ + col] = acc[mf][nf][r];
            }
}

extern "C" void kernel_launch(void* const* d_in, const int* in_sizes, int n_in,
                              void* d_out, int out_size, void* d_ws, size_t ws_size,
                              hipStream_t stream) {
    const float* x = (const float*)d_in[0];
    // d_in[1] = tokens_per_expert: reference assumes equal split, unused.
    const float* w = (const float*)d_in[2];
    float* out = (float*)d_out;

    __bf16* xq = (__bf16*)d_ws;
    __bf16* wq = (__bf16*)((char*)d_ws + (size_t)SEQ * DIN_ * sizeof(__bf16));

    quant_x_kernel<<<SEQ / 4, 256, 0, stream>>>(x, xq);
    quant_w_kernel<<<(NE_ * DOUT_ / 128) * (DIN_ / 128), 256, 0, stream>>>(w, wq);
    gemm_kernel<<<NE_ * (TPE / 256) * (DOUT_ / 256), 512, 0, stream>>>(xq, wq, out);
}

// Round 11
// 128.121 us; speedup vs baseline: 1.0132x; 1.0132x over previous
//
#include <hip/hip_runtime.h>
#include <hip/hip_bf16.h>
#include <hip/hip_fp8.h>

// Problem shape (fixed by setup_inputs)
#define SEQ   16384
#define DIN_  2048
#define DOUT_ 1024
#define NE_   8
#define TPE   (SEQ / NE_)   // 2048 tokens per expert
#define NT    (DIN_ / 64)   // 32 K-tiles of 64

typedef __bf16 bf16x8 __attribute__((ext_vector_type(8)));
typedef __bf16 bf16x4 __attribute__((ext_vector_type(4)));
typedef float  f32x4  __attribute__((ext_vector_type(4)));

// async global->LDS, 16B per lane. LDS dest must be wave-linear (base + lane*16).
#define GLD(gp, lp) __builtin_amdgcn_global_load_lds( \
    (const __attribute__((address_space(1))) unsigned int*)(gp), \
    (__attribute__((address_space(3))) unsigned int*)(lp), 16, 0, 0)

// Reference fp8_round with the tile-wide divide hoisted: r = v*(1/scale)
__device__ __forceinline__ float fp8_round_dq_m(float v, float sinv, float s) {
    float r = v * sinv;
    r = fminf(fmaxf(r, -448.0f), 448.0f);
    __hip_fp8_e4m3 q(r);   // OCP e4m3fn, RNE, saturated
    return (float)q * s;
}

// ---------------- activation quant-dequant: 1x128 tiles, 4 rows per block ----------------
__global__ __launch_bounds__(256) void quant_x_kernel(const float* __restrict__ X,
                                                      __bf16* __restrict__ Xq) {
    const int t    = threadIdx.x;
    const int lane = t & 63;
    const int wave = t >> 6;
    const int tile = wave * 4 + (lane >> 4);   // 0..15
    const int sub  = lane & 15;
    const size_t off = (size_t)tile * 128 + sub * 8;

    const int row0 = blockIdx.x * 4;
    float4 v0[4], v1[4];
    float mx[4];
    #pragma unroll
    for (int r = 0; r < 4; ++r) {
        const float* p = X + (size_t)(row0 + r) * DIN_ + off;
        v0[r] = *(const float4*)p;
        v1[r] = *(const float4*)(p + 4);
        mx[r] = fmaxf(fmaxf(fmaxf(fabsf(v0[r].x), fabsf(v0[r].y)),
                            fmaxf(fabsf(v0[r].z), fabsf(v0[r].w))),
                      fmaxf(fmaxf(fabsf(v1[r].x), fabsf(v1[r].y)),
                            fmaxf(fabsf(v1[r].z), fabsf(v1[r].w))));
    }
    #pragma unroll
    for (int o = 1; o < 16; o <<= 1) {
        #pragma unroll
        for (int r = 0; r < 4; ++r)
            mx[r] = fmaxf(mx[r], __shfl_xor(mx[r], o, 64));
    }
    #pragma unroll
    for (int r = 0; r < 4; ++r) {
        const float s    = fmaxf(mx[r], 1e-12f) / 448.0f;
        const float sinv = 1.0f / s;
        bf16x8 o;
        o[0] = (__bf16)fp8_round_dq_m(v0[r].x, sinv, s);
        o[1] = (__bf16)fp8_round_dq_m(v0[r].y, sinv, s);
        o[2] = (__bf16)fp8_round_dq_m(v0[r].z, sinv, s);
        o[3] = (__bf16)fp8_round_dq_m(v0[r].w, sinv, s);
        o[4] = (__bf16)fp8_round_dq_m(v1[r].x, sinv, s);
        o[5] = (__bf16)fp8_round_dq_m(v1[r].y, sinv, s);
        o[6] = (__bf16)fp8_round_dq_m(v1[r].z, sinv, s);
        o[7] = (__bf16)fp8_round_dq_m(v1[r].w, sinv, s);
        *(bf16x8*)(Xq + (size_t)(row0 + r) * DIN_ + off) = o;
    }
}

// ---------------- weight quant-dequant: 128x128 blocks ----------------
__global__ __launch_bounds__(256) void quant_w_kernel(const float* __restrict__ W,
                                                      __bf16* __restrict__ Wq) {
    const int rb = blockIdx.x >> 4;
    const int cb = blockIdx.x & 15;
    const int t  = threadIdx.x;

    const float* base = W + (size_t)(rb * 128) * DIN_ + cb * 128;
    const int r0 = t >> 5;
    const int c0 = (t & 31) * 4;

    float4 v[16];
    float m = 0.0f;
    #pragma unroll
    for (int i = 0; i < 16; ++i) {
        v[i] = *(const float4*)(base + (size_t)(i * 8 + r0) * DIN_ + c0);
        m = fmaxf(m, fmaxf(fmaxf(fabsf(v[i].x), fabsf(v[i].y)),
                           fmaxf(fabsf(v[i].z), fabsf(v[i].w))));
    }
    #pragma unroll
    for (int off = 1; off < 64; off <<= 1)
        m = fmaxf(m, __shfl_xor(m, off, 64));
    __shared__ float smx[4];
    if ((t & 63) == 0) smx[t >> 6] = m;
    __syncthreads();
    const float amax = fmaxf(fmaxf(smx[0], smx[1]), fmaxf(smx[2], smx[3]));
    const float s    = fmaxf(amax, 1e-12f) / 448.0f;
    const float sinv = 1.0f / s;

    __bf16* obase = Wq + (size_t)(rb * 128) * DIN_ + cb * 128;
    #pragma unroll
    for (int i = 0; i < 16; ++i) {
        bf16x4 o;
        o[0] = (__bf16)fp8_round_dq_m(v[i].x, sinv, s);
        o[1] = (__bf16)fp8_round_dq_m(v[i].y, sinv, s);
        o[2] = (__bf16)fp8_round_dq_m(v[i].z, sinv, s);
        o[3] = (__bf16)fp8_round_dq_m(v[i].w, sinv, s);
        *(bf16x4*)(obase + (size_t)(i * 8 + r0) * DIN_ + c0) = o;
    }
}

// ---------------- grouped GEMM: 256x256, BK=64, 16x16x32, WAVE-SLIP schedule -----------
// Layout identical to R8: 4 regions [256 rows][128 B], swizzle slot(3b) ^= row&7,
// lane-linear GLD dest, inverse-swizzled 128B-coalesced source, 16x16x32 fragments.
// NEW: no mid-tile barriers. Waves slip through the 4 phases; per-wave ordering via
// counted lgkmcnt only. m114: independent waves overlap MFMA and LDS pipes.
// Per-tile ledger (ds_read issue counts / lgkm gates):
//   top: aA(4)+b0(4)    ph1: +aB(4), lgkm(4)  ph2: +aA'(4)+b1(4), lgkm(8)
//   ph3: +aB'(4), lgkm(4)               ph4: lgkm(0)  -> all buf(kt) reads drained
// Boundary (only sync): barrier#1 (all waves drained buf(kt) reads) -> stage(kt+2)
//   -> vmcnt(8) [tail: 0] proves own kt+1-stages landed -> barrier#2 broadcasts.
// Max slip = 1 tile: fast wave parks at barrier#1 before any overwrite of buf^1.
__global__ __launch_bounds__(512, 2) void gemm_kernel(const __bf16* __restrict__ X,
                                                      const __bf16* __restrict__ W,
                                                      float* __restrict__ out) {
    __shared__ __align__(16) unsigned char lds[131072];

    // T1: bijective XCD swizzle; 256 blocks = 8 XCDs x 32 (one expert per XCD)
    const int bid  = blockIdx.x;
    const int wgid = (bid & 7) * 32 + (bid >> 3);
    const int e    = wgid >> 5;
    const int tile = wgid & 31;
    const int brow = tile >> 2;   // 0..7
    const int bcol = tile & 3;    // 0..3

    const int t     = threadIdx.x;
    const int lane  = t & 63;
    const int wave  = t >> 6;
    const int wm    = wave >> 2;  // 0..1
    const int wn    = wave & 3;   // 0..3
    const int flane = lane & 15;

    const __bf16* Xt = X + (size_t)(e * TPE + brow * 256) * DIN_;
    const __bf16* Wt = W + (size_t)(e * DOUT_ + bcol * 256) * DIN_;

    // stage one full tile (32 KiB): 4 GLD16/thread, linear dest, inverse-swizzled source
    auto stage = [&](int j, bool isA) {
        if (j >= NT) return;
        const unsigned base = (isA ? 0u : 65536u) + (unsigned)(j & 1) * 32768u;
        const __bf16* src = isA ? Xt : Wt;
        #pragma unroll
        for (int i = 0; i < 4; ++i) {
            const unsigned p = (unsigned)i * 8192u + (unsigned)t * 16u;
            const unsigned q = p ^ (((p >> 7) & 7u) << 4);   // involution
            GLD(src + (size_t)(q >> 7) * DIN_ + j * 64 + ((q & 127u) >> 1),
                &lds[base + p]);
        }
    };

    auto ldf = [&](unsigned base, int row, int kh) -> bf16x8 {
        unsigned p = (unsigned)row * 128u + (unsigned)kh * 64u + (unsigned)(lane >> 4) * 16u;
        p ^= ((p >> 7) & 7u) << 4;
        return *(const bf16x8*)&lds[base + p];
    };

    bf16x8 aA[4], aB[4], b0[4], b1[4];
    f32x4 acc[8][4] = {};

    #define ABASE(buf) ((unsigned)(buf) * 32768u)
    #define BBASE(buf) (65536u + (unsigned)(buf) * 32768u)
    #define PRE_A(dst, buf, kh, m0) \
        { _Pragma("unroll") for (int m_ = 0; m_ < 4; ++m_) \
            dst[m_] = ldf(ABASE(buf), wm * 128 + ((m0) + m_) * 16 + flane, kh); }
    #define PRE_B(dst, buf, kh) \
        { _Pragma("unroll") for (int n_ = 0; n_ < 4; ++n_) \
            dst[n_] = ldf(BBASE(buf), wn * 64 + n_ * 16 + flane, kh); }
    #define MFMA4x4(alo, aset, bset) \
        { _Pragma("unroll") for (int m_ = 0; m_ < 4; ++m_) \
            _Pragma("unroll") for (int n_ = 0; n_ < 4; ++n_) \
                acc[(alo) + m_][n_] = __builtin_amdgcn_mfma_f32_16x16x32_bf16( \
                    aset[m_], bset[n_], acc[(alo) + m_][n_], 0, 0, 0); }
    #define LGKM(n) \
        asm volatile("s_waitcnt lgkmcnt(" #n ")" ::: "memory"); \
        __builtin_amdgcn_sched_barrier(0);

    // prologue: tiles 0,1 (16 GLD, tile0 oldest); wait tile0 landed
    stage(0, false); stage(0, true); stage(1, false); stage(1, true);
    asm volatile("s_waitcnt vmcnt(8)" ::: "memory");
    __builtin_amdgcn_s_barrier();

    for (int kt = 0; kt < NT; ++kt) {
        const int buf = kt & 1;

        // top: this tile's first fragment set
        PRE_A(aA, buf, 0, 0);
        PRE_B(b0, buf, 0);

        // ---- phase 1: kh0 m0-3 ----
        PRE_A(aB, buf, 0, 4);                 // for ph2
        LGKM(4)                               // aA,b0 drained
        __builtin_amdgcn_s_setprio(1);
        MFMA4x4(0, aA, b0);
        __builtin_amdgcn_s_setprio(0);

        // ---- phase 2: kh0 m4-7 ----
        PRE_A(aA, buf, 1, 0);                 // for ph3 (kh1 m0-3)
        PRE_B(b1, buf, 1);
        LGKM(8)                               // aB drained
        __builtin_amdgcn_s_setprio(1);
        MFMA4x4(4, aB, b0);
        __builtin_amdgcn_s_setprio(0);

        // ---- phase 3: kh1 m0-3 ----
        PRE_A(aB, buf, 1, 4);                 // for ph4
        LGKM(4)                               // aA',b1 drained
        __builtin_amdgcn_s_setprio(1);
        MFMA4x4(0, aA, b1);
        __builtin_amdgcn_s_setprio(0);

        // ---- phase 4: kh1 m4-7 ----
        LGKM(0)                               // all buf(kt) reads drained
        __builtin_amdgcn_s_setprio(1);
        MFMA4x4(4, aB, b1);
        __builtin_amdgcn_s_setprio(0);

        // ---- K-tile boundary (only synchronization) ----
        __builtin_amdgcn_s_barrier();         // all waves done reading buf(kt)
        stage(kt + 2, false);
        stage(kt + 2, true);
        if (kt < NT - 2) asm volatile("s_waitcnt vmcnt(8)" ::: "memory");
        else             asm volatile("s_waitcnt vmcnt(0)" ::: "memory");
        __builtin_amdgcn_s_barrier();         // kt+1 data visible to all waves
    }

    // epilogue: C/D mapping col = lane&15, row = (lane>>4)*4 + j
    const int orow0 = e * TPE + brow * 256 + wm * 128;
    const int ocol0 = bcol * 256 + wn * 64;
    const int rl = (lane >> 4) * 4;
    const int cl = lane & 15;
    #pragma unroll
    for (int m = 0; m < 8; ++m)
        #pragma unroll
        for (int n = 0; n < 4; ++n)
            #pragma unroll
            for (int j = 0; j < 4; ++j) {
                const int r = orow0 + m * 16 + rl + j;
                const int c = ocol0 + n * 16 + cl;
                out[(size_t)r * DOUT_ + c] = acc[m][n][j];
            }
}

extern "C" void kernel_launch(void* const* d_in, const int* in_sizes, int n_in,
                              void* d_out, int out_size, void* d_ws, size_t ws_size,
                              hipStream_t stream) {
    const float* x = (const float*)d_in[0];
    // d_in[1] = tokens_per_expert: reference assumes equal split, unused.
    const float* w = (const float*)d_in[2];
    float* out = (float*)d_out;

    __bf16* xq = (__bf16*)d_ws;
    __bf16* wq = (__bf16*)((char*)d_ws + (size_t)SEQ * DIN_ * sizeof(__bf16));

    quant_x_kernel<<<SEQ / 4, 256, 0, stream>>>(x, xq);
    quant_w_kernel<<<(NE_ * DOUT_ / 128) * (DIN_ / 128), 256, 0, stream>>>(w, wq);
    gemm_kernel<<<NE_ * (TPE / 256) * (DOUT_ / 256), 512, 0, stream>>>(xq, wq, out);
}

// Round 12
// 123.899 us; speedup vs baseline: 1.0477x; 1.0341x over previous
//
#include <hip/hip_runtime.h>
#include <hip/hip_bf16.h>
#include <hip/hip_fp8.h>

// Problem shape (fixed by setup_inputs)
#define SEQ   16384
#define DIN_  2048
#define DOUT_ 1024
#define NE_   8
#define TPE   (SEQ / NE_)   // 2048 tokens per expert
#define NT    (DIN_ / 64)   // 32 K-tiles of 64

typedef __bf16 bf16x8 __attribute__((ext_vector_type(8)));
typedef __bf16 bf16x4 __attribute__((ext_vector_type(4)));
typedef float  f32x4  __attribute__((ext_vector_type(4)));

// async global->LDS, 16B per lane. LDS dest must be wave-linear (base + lane*16).
#define GLD(gp, lp) __builtin_amdgcn_global_load_lds( \
    (const __attribute__((address_space(1))) unsigned int*)(gp), \
    (__attribute__((address_space(3))) unsigned int*)(lp), 16, 0, 0)

// Reference fp8_round with the tile-wide divide hoisted: r = v*(1/scale)
__device__ __forceinline__ float fp8_round_dq_m(float v, float sinv, float s) {
    float r = v * sinv;
    r = fminf(fmaxf(r, -448.0f), 448.0f);
    __hip_fp8_e4m3 q(r);   // OCP e4m3fn, RNE, saturated
    return (float)q * s;
}

// ---------------- activation quant-dequant: 1x128 tiles, 4 rows per block ----------------
__global__ __launch_bounds__(256) void quant_x_kernel(const float* __restrict__ X,
                                                      __bf16* __restrict__ Xq) {
    const int t    = threadIdx.x;
    const int lane = t & 63;
    const int wave = t >> 6;
    const int tile = wave * 4 + (lane >> 4);   // 0..15
    const int sub  = lane & 15;
    const size_t off = (size_t)tile * 128 + sub * 8;

    const int row0 = blockIdx.x * 4;
    float4 v0[4], v1[4];
    float mx[4];
    #pragma unroll
    for (int r = 0; r < 4; ++r) {
        const float* p = X + (size_t)(row0 + r) * DIN_ + off;
        v0[r] = *(const float4*)p;
        v1[r] = *(const float4*)(p + 4);
        mx[r] = fmaxf(fmaxf(fmaxf(fabsf(v0[r].x), fabsf(v0[r].y)),
                            fmaxf(fabsf(v0[r].z), fabsf(v0[r].w))),
                      fmaxf(fmaxf(fabsf(v1[r].x), fabsf(v1[r].y)),
                            fmaxf(fabsf(v1[r].z), fabsf(v1[r].w))));
    }
    #pragma unroll
    for (int o = 1; o < 16; o <<= 1) {
        #pragma unroll
        for (int r = 0; r < 4; ++r)
            mx[r] = fmaxf(mx[r], __shfl_xor(mx[r], o, 64));
    }
    #pragma unroll
    for (int r = 0; r < 4; ++r) {
        const float s    = fmaxf(mx[r], 1e-12f) / 448.0f;
        const float sinv = 1.0f / s;
        bf16x8 o;
        o[0] = (__bf16)fp8_round_dq_m(v0[r].x, sinv, s);
        o[1] = (__bf16)fp8_round_dq_m(v0[r].y, sinv, s);
        o[2] = (__bf16)fp8_round_dq_m(v0[r].z, sinv, s);
        o[3] = (__bf16)fp8_round_dq_m(v0[r].w, sinv, s);
        o[4] = (__bf16)fp8_round_dq_m(v1[r].x, sinv, s);
        o[5] = (__bf16)fp8_round_dq_m(v1[r].y, sinv, s);
        o[6] = (__bf16)fp8_round_dq_m(v1[r].z, sinv, s);
        o[7] = (__bf16)fp8_round_dq_m(v1[r].w, sinv, s);
        *(bf16x8*)(Xq + (size_t)(row0 + r) * DIN_ + off) = o;
    }
}

// ---------------- weight quant-dequant: 128x128 blocks ----------------
__global__ __launch_bounds__(256) void quant_w_kernel(const float* __restrict__ W,
                                                      __bf16* __restrict__ Wq) {
    const int rb = blockIdx.x >> 4;
    const int cb = blockIdx.x & 15;
    const int t  = threadIdx.x;

    const float* base = W + (size_t)(rb * 128) * DIN_ + cb * 128;
    const int r0 = t >> 5;
    const int c0 = (t & 31) * 4;

    float4 v[16];
    float m = 0.0f;
    #pragma unroll
    for (int i = 0; i < 16; ++i) {
        v[i] = *(const float4*)(base + (size_t)(i * 8 + r0) * DIN_ + c0);
        m = fmaxf(m, fmaxf(fmaxf(fabsf(v[i].x), fabsf(v[i].y)),
                           fmaxf(fabsf(v[i].z), fabsf(v[i].w))));
    }
    #pragma unroll
    for (int off = 1; off < 64; off <<= 1)
        m = fmaxf(m, __shfl_xor(m, off, 64));
    __shared__ float smx[4];
    if ((t & 63) == 0) smx[t >> 6] = m;
    __syncthreads();
    const float amax = fmaxf(fmaxf(smx[0], smx[1]), fmaxf(smx[2], smx[3]));
    const float s    = fmaxf(amax, 1e-12f) / 448.0f;
    const float sinv = 1.0f / s;

    __bf16* obase = Wq + (size_t)(rb * 128) * DIN_ + cb * 128;
    #pragma unroll
    for (int i = 0; i < 16; ++i) {
        bf16x4 o;
        o[0] = (__bf16)fp8_round_dq_m(v[i].x, sinv, s);
        o[1] = (__bf16)fp8_round_dq_m(v[i].y, sinv, s);
        o[2] = (__bf16)fp8_round_dq_m(v[i].z, sinv, s);
        o[3] = (__bf16)fp8_round_dq_m(v[i].w, sinv, s);
        *(bf16x4*)(obase + (size_t)(i * 8 + r0) * DIN_ + c0) = o;
    }
}

// ---------------- grouped GEMM: 128x128 tile, BK=64, 2 BLOCKS/CU ------------------------
// NEW AXIS: occupancy. 64 KB LDS/block -> 2 independent blocks per CU; when one block
// stalls (lgkm gate / boundary barrier+vmcnt), the other's MFMAs and ds_reads fill the
// pipes (m114 overlap at block granularity). 4 waves (2Mx2N), wave tile 64x64.
// LDS: A(buf) @ buf*16384, B(buf) @ 32768 + buf*16384; regions [128 rows][128 B].
// Swizzle (R11-proven, 0 conflicts): byte p ^= ((p>>7)&7)<<4; lane-linear GLD dest,
// inverse-swizzled 128B-coalesced source.
// Schedule per K-tile (2 phases x 16 MFMA):
//   top(prev boundary): pre a0,b0 = kstep0 (8 reads, from buf)
//   ph1: pre a1,b1 = kstep1 (8); lgkm(8) [drains a0,b0]; MFMA16(ks0)
//   ph2: lgkm(0) [drains a1,b1];                          MFMA16(ks1)
//   boundary: barrier  [all waves drained buf(kt) reads]
//             stage(kt+2) [8 GLD: A 4 + B 4]
//             vmcnt(8) [kt+2's 8 newest remain => kt+1 landed] ; tail kt>=NT-2: vmcnt(0)
//             barrier  [kt+1 visible] ; pre next a0,b0 from buf^1
__global__ __launch_bounds__(256, 2) void gemm_kernel(const __bf16* __restrict__ X,
                                                      const __bf16* __restrict__ W,
                                                      float* __restrict__ out) {
    __shared__ __align__(16) unsigned char lds[65536];

    // T1: bijective XCD swizzle; 1024 blocks = 8 XCDs x 128 (one expert per XCD)
    const int bid  = blockIdx.x;
    const int wgid = (bid & 7) * 128 + (bid >> 3);
    const int e    = wgid >> 7;
    const int rem  = wgid & 127;
    const int brow = rem >> 3;    // 0..15
    const int bcol = rem & 7;     // 0..7

    const int t     = threadIdx.x;
    const int lane  = t & 63;
    const int wave  = t >> 6;
    const int wm    = wave >> 1;  // 0..1
    const int wn    = wave & 1;   // 0..1
    const int flane = lane & 15;

    const __bf16* Xt = X + (size_t)(e * TPE + brow * 128) * DIN_;
    const __bf16* Wt = W + (size_t)(e * DOUT_ + bcol * 128) * DIN_;

    // stage tile kt: A (16 KB, 4 GLD) + B (16 KB, 4 GLD); linear dest, inv-swz source
    auto stage = [&](int j) {
        if (j >= NT) return;
        const unsigned ab = (unsigned)(j & 1) * 16384u;
        #pragma unroll
        for (int i = 0; i < 4; ++i) {
            const unsigned p = (unsigned)i * 4096u + (unsigned)t * 16u;
            const unsigned q = p ^ (((p >> 7) & 7u) << 4);   // involution
            GLD(Xt + (size_t)(q >> 7) * DIN_ + j * 64 + ((q & 127u) >> 1), &lds[ab + p]);
        }
        #pragma unroll
        for (int i = 0; i < 4; ++i) {
            const unsigned p = (unsigned)i * 4096u + (unsigned)t * 16u;
            const unsigned q = p ^ (((p >> 7) & 7u) << 4);
            GLD(Wt + (size_t)(q >> 7) * DIN_ + j * 64 + ((q & 127u) >> 1),
                &lds[32768u + ab + p]);
        }
    };

    auto ldf = [&](unsigned base, int row, int ks) -> bf16x8 {
        unsigned p = (unsigned)row * 128u + (unsigned)ks * 64u + (unsigned)(lane >> 4) * 16u;
        p ^= ((p >> 7) & 7u) << 4;
        return *(const bf16x8*)&lds[base + p];
    };

    bf16x8 a0[4], a1[4], b0[4], b1[4];
    f32x4 acc[4][4] = {};

    #define PRE8(adst, bdst, buf, ks) \
        { _Pragma("unroll") for (int m_ = 0; m_ < 4; ++m_) \
            adst[m_] = ldf((unsigned)(buf) * 16384u, wm * 64 + m_ * 16 + flane, ks); \
          _Pragma("unroll") for (int n_ = 0; n_ < 4; ++n_) \
            bdst[n_] = ldf(32768u + (unsigned)(buf) * 16384u, wn * 64 + n_ * 16 + flane, ks); }
    #define MFMA16(aset, bset) \
        { _Pragma("unroll") for (int m_ = 0; m_ < 4; ++m_) \
            _Pragma("unroll") for (int n_ = 0; n_ < 4; ++n_) \
                acc[m_][n_] = __builtin_amdgcn_mfma_f32_16x16x32_bf16( \
                    aset[m_], bset[n_], acc[m_][n_], 0, 0, 0); }

    // prologue: tiles 0,1 (16 GLD, tile0 oldest); wait tile0 landed
    stage(0); stage(1);
    asm volatile("s_waitcnt vmcnt(8)" ::: "memory");
    __builtin_amdgcn_s_barrier();
    PRE8(a0, b0, 0, 0);

    for (int kt = 0; kt < NT; ++kt) {
        const int buf = kt & 1;

        // ---- phase 1: kstep0 ----
        PRE8(a1, b1, buf, 1);
        asm volatile("s_waitcnt lgkmcnt(8)" ::: "memory");   // a0,b0 drained
        __builtin_amdgcn_sched_barrier(0);
        __builtin_amdgcn_s_setprio(1);
        MFMA16(a0, b0);
        __builtin_amdgcn_s_setprio(0);

        // ---- phase 2: kstep1 ----
        asm volatile("s_waitcnt lgkmcnt(0)" ::: "memory");   // a1,b1 drained
        __builtin_amdgcn_sched_barrier(0);
        __builtin_amdgcn_s_setprio(1);
        MFMA16(a1, b1);
        __builtin_amdgcn_s_setprio(0);

        // ---- K-tile boundary ----
        __builtin_amdgcn_s_barrier();         // all waves done reading buf(kt)
        stage(kt + 2);
        if (kt < NT - 2) asm volatile("s_waitcnt vmcnt(8)" ::: "memory");
        else             asm volatile("s_waitcnt vmcnt(0)" ::: "memory");
        __builtin_amdgcn_s_barrier();         // kt+1 data visible
        if (kt < NT - 1) PRE8(a0, b0, buf ^ 1, 0);
    }

    // epilogue: C/D mapping col = lane&15, row = (lane>>4)*4 + j
    const int orow0 = e * TPE + brow * 128 + wm * 64;
    const int ocol0 = bcol * 128 + wn * 64;
    const int rl = (lane >> 4) * 4;
    const int cl = lane & 15;
    #pragma unroll
    for (int m = 0; m < 4; ++m)
        #pragma unroll
        for (int n = 0; n < 4; ++n)
            #pragma unroll
            for (int j = 0; j < 4; ++j) {
                const int r = orow0 + m * 16 + rl + j;
                const int c = ocol0 + n * 16 + cl;
                out[(size_t)r * DOUT_ + c] = acc[m][n][j];
            }
}

extern "C" void kernel_launch(void* const* d_in, const int* in_sizes, int n_in,
                              void* d_out, int out_size, void* d_ws, size_t ws_size,
                              hipStream_t stream) {
    const float* x = (const float*)d_in[0];
    // d_in[1] = tokens_per_expert: reference assumes equal split, unused.
    const float* w = (const float*)d_in[2];
    float* out = (float*)d_out;

    __bf16* xq = (__bf16*)d_ws;
    __bf16* wq = (__bf16*)((char*)d_ws + (size_t)SEQ * DIN_ * sizeof(__bf16));

    quant_x_kernel<<<SEQ / 4, 256, 0, stream>>>(x, xq);
    quant_w_kernel<<<(NE_ * DOUT_ / 128) * (DIN_ / 128), 256, 0, stream>>>(w, wq);
    gemm_kernel<<<NE_ * (TPE / 128) * (DOUT_ / 128), 256, 0, stream>>>(xq, wq, out);
}